// Round 4
// baseline (333.537 us; speedup 1.0000x reference)
//
#include <hip/hip_runtime.h>
#include <cstddef>

#define NB 64
#define LL 512
#define HH 256
#define HD 128
#define NG 512
#define TI 16

typedef _Float16 half_t;
typedef _Float16 half8 __attribute__((ext_vector_type(8)));
typedef _Float16 half4 __attribute__((ext_vector_type(4)));
typedef float f32x4 __attribute__((ext_vector_type(4)));

#define MFMA16(a, b, c) __builtin_amdgcn_mfma_f32_16x16x32_f16((a), (b), (c), 0, 0, 0)

// LDS pitches (dword stride ≡ 4 mod 32 -> <=2-way bank aliasing, free on CDNA4)
#define FP  264   // sFeatb pitch (halves): 132 dw
#define XP2 520   // sXGh  pitch (halves): 260 dw
#define HBP 136   // sHb   pitch (halves): 68 dw

// fast sigmoid/tanh: raw v_exp_f32 + v_rcp_f32 (~1 ulp each; threshold is 9.7e-3)
__device__ __forceinline__ float fsigm(float x) {
    return __builtin_amdgcn_rcpf(1.0f + __builtin_amdgcn_exp2f(-1.44269504f * x));
}
__device__ __forceinline__ float ftanh(float x) {
    return 2.0f * __builtin_amdgcn_rcpf(1.0f + __builtin_amdgcn_exp2f(-2.88539008f * x)) - 1.0f;
}

// ---- prep: cast weights to f16 (row-major [g][k] = B-fragment layout), bsum = b_ih+b_hh ----
__global__ void prep_weights(const float* __restrict__ Wih, const float* __restrict__ Whh,
                             const float* __restrict__ bih, const float* __restrict__ bhh,
                             half_t* __restrict__ WihH, half_t* __restrict__ WhhH,
                             float* __restrict__ bsum)
{
    const int idx = blockIdx.x * 256 + threadIdx.x;
    if (idx < NG * HH) WihH[idx] = (half_t)Wih[idx];
    if (idx < NG * HD) WhhH[idx] = (half_t)Whh[idx];
    if (idx < NG)      bsum[idx] = bih[idx] + bhh[idx];
}

__global__ __launch_bounds__(256, 4) void span_lstm_v4(
    const float* __restrict__ feats, const half_t* __restrict__ WihH,
    const half_t* __restrict__ WhhH, const float* __restrict__ bsum,
    const float* __restrict__ W_tri, const float* __restrict__ b_tri,
    const int* __restrict__ lens, float* __restrict__ out)
{
    // LDS: 10560 + 20800 + 8704 + 512 = 40576 B -> 4 blocks/CU
    __shared__ __align__(16) half_t sFeatb[20 * FP];
    __shared__ __align__(16) half_t sXGh[20 * XP2];
    __shared__ __align__(16) half_t sHb[2][16 * HBP];
    __shared__ float sEmitAll[16][8];

    const int tid = threadIdx.x;
    const int b  = blockIdx.x >> 5;
    const int i0 = (blockIdx.x & 31) * TI;
    const int lens_b = lens[b];

    // ---- stage feats window as f16 (coalesced float4 global reads) ----
    for (int idx = tid; idx < 20 * 64; idx += 256) {
        const int p  = idx >> 6;
        const int k4 = (idx & 63) << 2;
        const int gp = i0 + p;
        float4 v = make_float4(0.f, 0.f, 0.f, 0.f);
        if (gp < LL) v = *(const float4*)(feats + ((size_t)b * LL + gp) * HH + k4);
        half4 hv = {(half_t)v.x, (half_t)v.y, (half_t)v.z, (half_t)v.w};
        *(half4*)(&sFeatb[p * FP + k4]) = hv;
    }
    if (tid < 128) ((float*)sEmitAll)[tid] = 0.f;
    __syncthreads();

    const int lane = tid & 63, wv = tid >> 6;
    const int lm = lane & 15;          // m / n within 16-tile
    const int lq = lane >> 4;          // quad

    // ---- phase 1 (MFMA): XG[p][g] = sum_k F[p][k] * Wih[g][k] + bsum[g] ----
    {
        // A-frags: 2 M-tiles x 8 K-frags. Tile 1 rows 16..31 clamped to 19: MFMA D-rows
        // depend only on same A-row, and only D rows 16..19 are kept.
        const int rowA1 = (16 + lm > 19) ? 19 : 16 + lm;
        half8 afr[2][8];
        #pragma unroll
        for (int kf = 0; kf < 8; ++kf) {
            afr[0][kf] = *(const half8*)(&sFeatb[lm * FP + kf * 32 + lq * 8]);
            afr[1][kf] = *(const half8*)(&sFeatb[rowA1 * FP + kf * 32 + lq * 8]);
        }
        const int gwv = wv * 128;
        for (int nt = 0; nt < 8; ++nt) {
            const int gb = gwv + nt * 16;
            const float bs = bsum[gb + lm];
            f32x4 acc0 = {0.f, 0.f, 0.f, 0.f}, acc1 = {0.f, 0.f, 0.f, 0.f};
            #pragma unroll
            for (int kf = 0; kf < 8; ++kf) {
                const half8 bfr = *(const half8*)(WihH + (size_t)(gb + lm) * HH + kf * 32 + lq * 8);
                acc0 = MFMA16(afr[0][kf], bfr, acc0);
                acc1 = MFMA16(afr[1][kf], bfr, acc1);
            }
            #pragma unroll
            for (int r = 0; r < 4; ++r)
                sXGh[(lq * 4 + r) * XP2 + gb + lm] = (half_t)(acc0[r] + bs);
            if (lq == 0) {
                #pragma unroll
                for (int r = 0; r < 4; ++r)
                    sXGh[(16 + r) * XP2 + gb + lm] = (half_t)(acc1[r] + bs);
            }
        }
    }
    __syncthreads();   // sXGh visible

    // ---- phase 2: 4-step recurrence, double-buffered f16 h, 1 barrier/step ----
    // wave wv owns j in [32wv, 32wv+32): 2 j-tiles x 4 gate types; cell fully in-lane.
    const int j0 = 32 * wv;
    float cc[2][4] = {{0.f, 0.f, 0.f, 0.f}, {0.f, 0.f, 0.f, 0.f}};

    for (int t = 0; t < 4; ++t) {
        const int wb = t & 1, rb = wb ^ 1;
        float accg[2][4][4];   // [jt][ta][r]
        if (t > 0) {
            half8 ah[4];
            #pragma unroll
            for (int kf = 0; kf < 4; ++kf)
                ah[kf] = *(const half8*)(&sHb[rb][lm * HBP + kf * 32 + lq * 8]);
            #pragma unroll
            for (int jt = 0; jt < 2; ++jt)
                #pragma unroll
                for (int ta = 0; ta < 4; ++ta) {
                    f32x4 a = {0.f, 0.f, 0.f, 0.f};
                    #pragma unroll
                    for (int kf = 0; kf < 4; ++kf) {
                        const half8 bfr = *(const half8*)(WhhH
                            + (size_t)(ta * HD + j0 + jt * 16 + lm) * HD + kf * 32 + lq * 8);
                        a = MFMA16(ah[kf], bfr, a);
                    }
                    #pragma unroll
                    for (int r = 0; r < 4; ++r) accg[jt][ta][r] = a[r];
                }
        } else {
            #pragma unroll
            for (int jt = 0; jt < 2; ++jt)
                #pragma unroll
                for (int ta = 0; ta < 4; ++ta)
                    #pragma unroll
                    for (int r = 0; r < 4; ++r) accg[jt][ta][r] = 0.f;
        }
        #pragma unroll
        for (int jt = 0; jt < 2; ++jt)
            #pragma unroll
            for (int ta = 0; ta < 4; ++ta)
                #pragma unroll
                for (int r = 0; r < 4; ++r)
                    accg[jt][ta][r] += (float)sXGh[(lq * 4 + r + t) * XP2 + ta * HD
                                                   + j0 + jt * 16 + lm];
        // cell update
        #pragma unroll
        for (int jt = 0; jt < 2; ++jt)
            #pragma unroll
            for (int r = 0; r < 4; ++r) {
                const float ig = fsigm(accg[jt][0][r]);
                const float fg = fsigm(accg[jt][1][r]);
                const float gg = ftanh(accg[jt][2][r]);
                const float og = fsigm(accg[jt][3][r]);
                cc[jt][r] = fg * cc[jt][r] + ig * gg;
                const float h = og * ftanh(cc[jt][r]);
                sHb[wb][(lq * 4 + r) * HBP + j0 + jt * 16 + lm] = (half_t)h;
            }
        __syncthreads();   // new sHb[wb] visible (also orders next step's overwrite of sHb[rb])

        // ---- emission (wave 0 only; other waves roll into next step's loads) ----
        if (tid < 64) {
            const int es = tid >> 2, etag = (tid >> 1) & 1, kc = tid & 1;
            const half_t* hp = &sHb[wb][es * HBP + kc * 64];
            const float*  wp = W_tri + (size_t)etag * HD + kc * 64;
            float part = 0.f;
            #pragma unroll
            for (int u = 0; u < 64; u += 4) {
                const half4 h4 = *(const half4*)(hp + u);
                const float4 w4 = *(const float4*)(wp + u);
                part += (float)h4.x * w4.x + (float)h4.y * w4.y
                      + (float)h4.z * w4.z + (float)h4.w * w4.w;
            }
            part += __shfl_xor(part, 1);
            if (kc == 0) {
                const int i = i0 + es, rem = lens_b - i, sc = t + 1;
                if (rem > 0 && sc <= rem) {
                    const float e = part + b_tri[etag];
                    const int mm  = rem < 4 ? rem : 4;
                    const int whi = (sc >= mm) ? 4 : sc;
                    for (int w2 = sc; w2 <= whi; ++w2)
                        sEmitAll[es][(w2 - 1) * 2 + etag] = e;
                }
            }
        }
    }
    __syncthreads();   // sEmitAll complete

    // ---- full output-tile write (replaces global memset; covers every element once) ----
    {
        const int row = tid >> 4;            // 0..15
        const int f4b = tid & 15;
        const int iG  = i0 + row;
        float* rowp = out + ((size_t)b * LL + iG) * LL * 2;
        #pragma unroll
        for (int cth = 0; cth < 16; ++cth) {
            const int f4 = f4b + 16 * cth;   // float4 index within row (0..255)
            const int c4 = f4 * 4;           // float col
            const int j1 = c4 >> 1;          // even j
            const int d1 = j1 - iG;
            float4 v = make_float4(0.f, 0.f, 0.f, 0.f);
            if ((unsigned)d1 < 4u) { v.x = sEmitAll[row][d1 * 2]; v.y = sEmitAll[row][d1 * 2 + 1]; }
            const int d2 = d1 + 1;
            if ((unsigned)d2 < 4u) { v.z = sEmitAll[row][d2 * 2]; v.w = sEmitAll[row][d2 * 2 + 1]; }
            *(float4*)(rowp + c4) = v;
        }
    }
}

extern "C" void kernel_launch(void* const* d_in, const int* in_sizes, int n_in,
                              void* d_out, int out_size, void* d_ws, size_t ws_size,
                              hipStream_t stream)
{
    const float* feats = (const float*)d_in[0];
    const float* W_ih  = (const float*)d_in[1];
    const float* W_hh  = (const float*)d_in[2];
    const float* b_ih  = (const float*)d_in[3];
    const float* b_hh  = (const float*)d_in[4];
    const float* W_tri = (const float*)d_in[5];
    const float* b_tri = (const float*)d_in[6];
    const int*   lens  = (const int*)d_in[7];
    float* out = (float*)d_out;

    // ws layout: WihH (256 KB) | WhhH (128 KB) | bsum (2 KB)
    half_t* WihH = (half_t*)d_ws;
    half_t* WhhH = WihH + (size_t)NG * HH;
    float*  bsum = (float*)(WhhH + (size_t)NG * HD);

    prep_weights<<<(NG * HH + 255) / 256, 256, 0, stream>>>(W_ih, W_hh, b_ih, b_hh,
                                                            WihH, WhhH, bsum);
    span_lstm_v4<<<NB * (LL / TI), 256, 0, stream>>>(feats, WihH, WhhH, bsum,
                                                     W_tri, b_tri, lens, out);
}